// Round 3
// baseline (8746.019 us; speedup 1.0000x reference)
//
#include <hip/hip_runtime.h>
#include <cstddef>

// DifferentiableRollout: x_{t+1} = x + DT * ( tanh([x,u]@W1 + b1) @ W2 + b2 )
// B=1024, T=200, SD=64, CD=32, H=512.  fp32 only (R0: fp32 reorder noise
// alone -> absmax 0.25 of 1.245 threshold; bf16 would amplify past it).
//
// R5-R7 post-mortem: with 80 weight floats/thread demanded (W1 48 + W2 32),
//   the allocator NEVER kept them resident -- VGPR_Count pinned at 60 across
//   __launch_bounds__(1024,4) (R6) and opaque asm pins (R7); code and timing
//   byte-identical all three rounds.  No scratch-spill signature in HBM
//   counters -> weights rematerialized from L2 every step: 327 KB/CU/step
//   = 16.7 TB over the rollout ~ 485 us at the 34.5 TB/s L2 ceiling.
//
// R8 (this round): make residency easy instead of forced.
//   - W2 (512x64 = 128 KB) moves to LDS, loaded from L2 ONCE per kernel.
//     GEMM2 reads it as conflict-free lane-consecutive ds_read_b32, each
//     value hoisted across the 4 batch rows.
//   - W1 stays register-split (48/thread); total demand drops ~110 -> ~80,
//     well under the 128 cap from __launch_bounds__(1024,4) -- the
//     comfortable regime where the allocator cooperates.  Pins kept.
//   - part1/hbuf aliased into one pbuf[4][512] (reader == writer thread),
//     freeing 8 KB so everything fits: 128K (W2) + 1.5K (xcT) + 8K (pbuf)
//     + 16K (part2) = 153.5 KB of 160 KB LDS.
//   - tanh phase balanced: g=0 finishes rows 0-1, g=1 rows 2-3 (each side
//     writes the OTHER's needed partials pre-barrier) -- halves the serial
//     tanh chain; previously 8 of 16 waves idled here.
//   Verify: VGPR_Count ~90-110, LDS_Block_Size ~157K, dur ~430-520 us.

constexpr int B_  = 1024;
constexpr int T_  = 200;
constexpr int SD_ = 64;
constexpr int CD_ = 32;
constexpr int H_  = 512;
constexpr int KD_ = SD_ + CD_;   // 96
constexpr float DT_ = 0.1f;
constexpr int ROWS_ = 4;
constexpr int THREADS_ = 1024;
constexpr int KHALF_ = 48;       // K split per g
constexpr int CHUNK_ = 32;       // W2 rows per wave (H / 16 waves)

__global__ __launch_bounds__(THREADS_, 4)
void rollout_w2lds_kernel(
    const float* __restrict__ x0,     // [B, SD]
    const float* __restrict__ ctrl,   // [B, T, CD]
    const float* __restrict__ W1,     // [KD, H]
    const float* __restrict__ b1,     // [H]
    const float* __restrict__ W2,     // [H, SD]
    const float* __restrict__ b2,     // [SD]
    float* __restrict__ out)          // [B, T+1, SD]
{
    __shared__ float w2s[H_][SD_];           // 128 KB: W2, loaded once
    __shared__ float xcT[KD_][ROWS_];        // state+control, transposed
    __shared__ float pbuf[ROWS_][H_];        // GEMM1 partials, then tanh acts
    __shared__ float part2[ROWS_][16][SD_];  // GEMM2 partials [r][wv][s]

    const int tid = threadIdx.x;
    const int r0  = blockIdx.x * ROWS_;

    // ---- GEMM1 mapping: half-column of W1 in registers ----
    const int j     = tid & (H_ - 1);   // 0..511
    const int g     = tid >> 9;         // 0 or 1 (wave-uniform)
    const int kbase = g * KHALF_;
    float w1p[KHALF_];
    #pragma unroll
    for (int i = 0; i < KHALF_; ++i)
        w1p[i] = W1[(size_t)(kbase + i) * H_ + j];       // coalesced
    #pragma unroll
    for (int i = 0; i < KHALF_; ++i) asm volatile("" : "+v"(w1p[i]));

    // ---- W2 -> LDS (flat coalesced copy, 8 float4 per thread) ----
    {
        const float4* __restrict__ src = (const float4*)W2;
        float4* dst = (float4*)&w2s[0][0];
        #pragma unroll
        for (int i = 0; i < 8; ++i)
            dst[i * THREADS_ + tid] = src[i * THREADS_ + tid];
    }

    // ---- GEMM2 mapping: wave wv covers H-slice [32wv, 32wv+32) ----
    const int wv = tid >> 6;            // 0..15 (wave id)
    const int sl = tid & 63;
    const int jb = wv * CHUNK_;

    const float bj = b1[j];

    // reduce/update mapping (tid < 256)
    const int rf = (tid >> 6) & 3;
    const int sf = tid & 63;
    const float bs = b2[sf];

    // ctrl loader: tids [512, 640) -- g==1 threads
    const int  lt = tid - 512;
    const bool loader = (lt >= 0) && (lt < ROWS_ * CD_);
    const int  lr = (lt >> 5) & 3;
    const int  lc = lt & 31;
    const size_t ctrl_base = (size_t)(r0 + lr) * T_ * CD_ + lc;

    // ---- init: x0 into xcT + states[:,0,:], ctrl[0] into xcT ----
    if (tid < ROWS_ * SD_) {
        const float v = x0[(size_t)(r0 + rf) * SD_ + sf];
        xcT[sf][rf] = v;
        out[(size_t)(r0 + rf) * (T_ + 1) * SD_ + sf] = v;
    }
    if (loader) xcT[SD_ + lc][lr] = ctrl[ctrl_base];
    __syncthreads();   // covers xcT init AND w2s copy

    for (int t = 0; t < T_; ++t) {
        // ---- prefetch next step's controls into a register ----
        float cpre = 0.f;
        if (loader && (t + 1 < T_))
            cpre = ctrl[ctrl_base + (size_t)(t + 1) * CD_];

        // ---- GEMM1 rank-48 partials: 4 rows per thread ----
        float a0 = 0.f, a1 = 0.f, a2 = 0.f, a3 = 0.f;
        #pragma unroll
        for (int i = 0; i < KHALF_; ++i) {
            const float4 xv = *(const float4*)&xcT[kbase + i][0];  // broadcast
            const float  w  = w1p[i];
            a0 += xv.x * w;
            a1 += xv.y * w;
            a2 += xv.z * w;
            a3 += xv.w * w;
        }
        // each half writes the partials the OTHER half will finish
        if (g == 0) { pbuf[2][j] = a2;  pbuf[3][j] = a3; }
        else        { pbuf[0][j] = a0;  pbuf[1][j] = a1; }
        __syncthreads();   // A: partials visible; step-t xcT reads done

        // ---- balanced tanh: g=0 rows 0-1, g=1 rows 2-3 ----
        if (g == 0) {
            pbuf[0][j] = tanhf(bj + a0 + pbuf[0][j]);
            pbuf[1][j] = tanhf(bj + a1 + pbuf[1][j]);
        } else {
            pbuf[2][j] = tanhf(bj + a2 + pbuf[2][j]);
            pbuf[3][j] = tanhf(bj + a3 + pbuf[3][j]);
            if (loader && (t + 1 < T_))
                xcT[SD_ + lc][lr] = cpre;   // step-t xcT reads done at A
        }
        __syncthreads();   // B: activations visible

        // ---- GEMM2: wave wv, j in [jb, jb+32), W2 from LDS ----
        {
            float p0 = 0.f, p1 = 0.f, p2 = 0.f, p3 = 0.f;
            #pragma unroll
            for (int i4 = 0; i4 < CHUNK_; i4 += 4) {
                // 4 W2 rows, lane-consecutive (conflict-free), reused x4 rows
                const float wa = w2s[jb + i4 + 0][sl];
                const float wb = w2s[jb + i4 + 1][sl];
                const float wc = w2s[jb + i4 + 2][sl];
                const float wd = w2s[jb + i4 + 3][sl];
                const float4 h0 = *(const float4*)&pbuf[0][jb + i4];
                const float4 h1 = *(const float4*)&pbuf[1][jb + i4];
                const float4 h2 = *(const float4*)&pbuf[2][jb + i4];
                const float4 h3 = *(const float4*)&pbuf[3][jb + i4];
                p0 += h0.x * wa + h0.y * wb + h0.z * wc + h0.w * wd;
                p1 += h1.x * wa + h1.y * wb + h1.z * wc + h1.w * wd;
                p2 += h2.x * wa + h2.y * wb + h2.z * wc + h2.w * wd;
                p3 += h3.x * wa + h3.y * wb + h3.z * wc + h3.w * wd;
            }
            part2[0][wv][sl] = p0;      // lane-consecutive: conflict-free
            part2[1][wv][sl] = p1;
            part2[2][wv][sl] = p2;
            part2[3][wv][sl] = p3;
        }
        __syncthreads();   // C: part2 visible

        // ---- 16-chunk reduce + state update: tid < 256 ----
        if (tid < ROWS_ * SD_) {
            float acc = part2[rf][0][sf];
            #pragma unroll
            for (int c = 1; c < 16; ++c) acc += part2[rf][c][sf];
            const float xnew = xcT[sf][rf] + DT_ * (acc + bs);
            xcT[sf][rf] = xnew;
            out[(size_t)(r0 + rf) * (T_ + 1) * SD_ + (size_t)(t + 1) * SD_ + sf] = xnew;
        }
        __syncthreads();   // D: new state visible; part2 reads done
    }
}

extern "C" void kernel_launch(void* const* d_in, const int* in_sizes, int n_in,
                              void* d_out, int out_size, void* d_ws, size_t ws_size,
                              hipStream_t stream) {
    const float* x0   = (const float*)d_in[0];
    const float* ctrl = (const float*)d_in[1];
    const float* W1   = (const float*)d_in[2];
    const float* b1   = (const float*)d_in[3];
    const float* W2   = (const float*)d_in[4];
    const float* b2   = (const float*)d_in[5];
    float* out = (float*)d_out;

    dim3 grid(B_ / ROWS_);      // 256 blocks -> 1 per CU (persistent)
    dim3 block(THREADS_);
    rollout_w2lds_kernel<<<grid, block, 0, stream>>>(x0, ctrl, W1, b1, W2, b2, out);
}

// Round 4
// 8364.195 us; speedup vs baseline: 1.0456x; 1.0456x over previous
//
#include <hip/hip_runtime.h>
#include <cstddef>

// DifferentiableRollout: x_{t+1} = x + DT * ( tanh([x,u]@W1 + b1) @ W2 + b2 )
// B=1024, T=200, SD=64, CD=32, H=512.  fp32 only (R0: fp32 reorder noise
// alone -> absmax 0.25 of 1.245 threshold; bf16 would amplify past it).
//
// R5-R7: 80 weight floats/thread demanded in registers -> allocator NEVER
//   complied (VGPR_Count=60 across launch_bounds(1024,4) and asm pins);
//   weights streamed from L2 every step (327 KB/CU/step).
// R8: W2 -> LDS (good, kept) + asm-pinned W1 (disaster): allocator granted
//   64 VGPRs and spilled the 48 pinned floats to scratch INSIDE the loop:
//   FETCH 13.9 GB + WRITE 14.6 GB (~10 GB each way = 196 KB/block/step),
//   3.3 TB/s HBM, 8746 us.  Conclusions: (1) >64 VGPR grants don't happen
//   at 1024 threads here; (2) pinning under that grant = scratch thrash;
//   (3) the only lever on weight traffic is WHERE weights live.
//
// R9 (this round): R8 structure minus the pins; W1 streams honestly.
//   - W2 (128 KB) LDS-resident, loaded from L2 once per kernel; GEMM2
//     reads lane-consecutive ds_read_b32 (conflict-free), each value
//     hoisted across 4 batch rows.
//   - W1 loaded inside the t-loop with explicit per-step global loads
//     (single base pointer + i*H offsets): 196 KB/CU/step from L2
//     (~3500 cyc/step at the per-CU L2 share), down 40% from R5-R7.
//   - Balanced tanh (g=0 rows 0-1, g=1 rows 2-3); pbuf aliases
//     partials/activations; ctrl prefetch by g=1 threads.
//   - LDS: 128K (w2s) + 1.5K (xcT) + 8K (pbuf) + 16K (part2) = 153.5 KB.
//   Model: max(VALU ~3900, L2 ~3500) cyc/step + barrier slack -> 420-500 us.
//   Verify: hbm_bytes back to ~6.7e7 (no scratch), LDS 157K, VALUBusy 55-70%.

constexpr int B_  = 1024;
constexpr int T_  = 200;
constexpr int SD_ = 64;
constexpr int CD_ = 32;
constexpr int H_  = 512;
constexpr int KD_ = SD_ + CD_;   // 96
constexpr float DT_ = 0.1f;
constexpr int ROWS_ = 4;
constexpr int THREADS_ = 1024;
constexpr int KHALF_ = 48;       // K split per g
constexpr int CHUNK_ = 32;       // W2 rows per wave (H / 16 waves)

__global__ __launch_bounds__(THREADS_)
void rollout_w2lds_stream_kernel(
    const float* __restrict__ x0,     // [B, SD]
    const float* __restrict__ ctrl,   // [B, T, CD]
    const float* __restrict__ W1,     // [KD, H]
    const float* __restrict__ b1,     // [H]
    const float* __restrict__ W2,     // [H, SD]
    const float* __restrict__ b2,     // [SD]
    float* __restrict__ out)          // [B, T+1, SD]
{
    __shared__ float w2s[H_][SD_];           // 128 KB: W2, loaded once
    __shared__ float xcT[KD_][ROWS_];        // state+control, transposed
    __shared__ float pbuf[ROWS_][H_];        // GEMM1 partials, then tanh acts
    __shared__ float part2[ROWS_][16][SD_];  // GEMM2 partials [r][wv][s]

    const int tid = threadIdx.x;
    const int r0  = blockIdx.x * ROWS_;

    // ---- GEMM1 mapping: thread (g, j) streams W1[kbase..kbase+48)[j] ----
    const int j     = tid & (H_ - 1);   // 0..511
    const int g     = tid >> 9;         // 0 or 1 (wave-uniform)
    const int kbase = g * KHALF_;
    const float* __restrict__ wcol = W1 + (size_t)kbase * H_ + j;

    // ---- W2 -> LDS (flat coalesced copy, 8 float4 per thread) ----
    {
        const float4* __restrict__ src = (const float4*)W2;
        float4* dst = (float4*)&w2s[0][0];
        #pragma unroll
        for (int i = 0; i < 8; ++i)
            dst[i * THREADS_ + tid] = src[i * THREADS_ + tid];
    }

    // ---- GEMM2 mapping: wave wv covers H-slice [32wv, 32wv+32) ----
    const int wv = tid >> 6;            // 0..15 (wave id)
    const int sl = tid & 63;
    const int jb = wv * CHUNK_;

    const float bj = b1[j];

    // reduce/update mapping (tid < 256)
    const int rf = (tid >> 6) & 3;
    const int sf = tid & 63;
    const float bs = b2[sf];

    // ctrl loader: tids [512, 640) -- g==1 threads
    const int  lt = tid - 512;
    const bool loader = (lt >= 0) && (lt < ROWS_ * CD_);
    const int  lr = (lt >> 5) & 3;
    const int  lc = lt & 31;
    const size_t ctrl_base = (size_t)(r0 + lr) * T_ * CD_ + lc;

    // ---- init: x0 into xcT + states[:,0,:], ctrl[0] into xcT ----
    if (tid < ROWS_ * SD_) {
        const float v = x0[(size_t)(r0 + rf) * SD_ + sf];
        xcT[sf][rf] = v;
        out[(size_t)(r0 + rf) * (T_ + 1) * SD_ + sf] = v;
    }
    if (loader) xcT[SD_ + lc][lr] = ctrl[ctrl_base];
    __syncthreads();   // covers xcT init AND w2s copy

    for (int t = 0; t < T_; ++t) {
        // ---- prefetch next step's controls into a register ----
        float cpre = 0.f;
        if (loader && (t + 1 < T_))
            cpre = ctrl[ctrl_base + (size_t)(t + 1) * CD_];

        // ---- GEMM1 rank-48 partials: W1 streamed from L2 this step ----
        float a0 = 0.f, a1 = 0.f, a2 = 0.f, a3 = 0.f;
        #pragma unroll
        for (int i = 0; i < KHALF_; ++i) {
            const float  w  = wcol[(size_t)i * H_];                // L2 hit
            const float4 xv = *(const float4*)&xcT[kbase + i][0];  // broadcast
            a0 += xv.x * w;
            a1 += xv.y * w;
            a2 += xv.z * w;
            a3 += xv.w * w;
        }
        // each half writes the partials the OTHER half will finish
        if (g == 0) { pbuf[2][j] = a2;  pbuf[3][j] = a3; }
        else        { pbuf[0][j] = a0;  pbuf[1][j] = a1; }
        __syncthreads();   // A: partials visible; step-t xcT reads done

        // ---- balanced tanh: g=0 rows 0-1, g=1 rows 2-3 ----
        if (g == 0) {
            pbuf[0][j] = tanhf(bj + a0 + pbuf[0][j]);
            pbuf[1][j] = tanhf(bj + a1 + pbuf[1][j]);
        } else {
            pbuf[2][j] = tanhf(bj + a2 + pbuf[2][j]);
            pbuf[3][j] = tanhf(bj + a3 + pbuf[3][j]);
            if (loader && (t + 1 < T_))
                xcT[SD_ + lc][lr] = cpre;   // step-t xcT reads done at A
        }
        __syncthreads();   // B: activations visible

        // ---- GEMM2: wave wv, j in [jb, jb+32), W2 from LDS ----
        {
            float p0 = 0.f, p1 = 0.f, p2 = 0.f, p3 = 0.f;
            #pragma unroll
            for (int i4 = 0; i4 < CHUNK_; i4 += 4) {
                // 4 W2 rows, lane-consecutive (conflict-free), reused x4 rows
                const float wa = w2s[jb + i4 + 0][sl];
                const float wb = w2s[jb + i4 + 1][sl];
                const float wc = w2s[jb + i4 + 2][sl];
                const float wd = w2s[jb + i4 + 3][sl];
                const float4 h0 = *(const float4*)&pbuf[0][jb + i4];
                const float4 h1 = *(const float4*)&pbuf[1][jb + i4];
                const float4 h2 = *(const float4*)&pbuf[2][jb + i4];
                const float4 h3 = *(const float4*)&pbuf[3][jb + i4];
                p0 += h0.x * wa + h0.y * wb + h0.z * wc + h0.w * wd;
                p1 += h1.x * wa + h1.y * wb + h1.z * wc + h1.w * wd;
                p2 += h2.x * wa + h2.y * wb + h2.z * wc + h2.w * wd;
                p3 += h3.x * wa + h3.y * wb + h3.z * wc + h3.w * wd;
            }
            part2[0][wv][sl] = p0;      // lane-consecutive: conflict-free
            part2[1][wv][sl] = p1;
            part2[2][wv][sl] = p2;
            part2[3][wv][sl] = p3;
        }
        __syncthreads();   // C: part2 visible

        // ---- 16-chunk reduce + state update: tid < 256 ----
        if (tid < ROWS_ * SD_) {
            float acc = part2[rf][0][sf];
            #pragma unroll
            for (int c = 1; c < 16; ++c) acc += part2[rf][c][sf];
            const float xnew = xcT[sf][rf] + DT_ * (acc + bs);
            xcT[sf][rf] = xnew;
            out[(size_t)(r0 + rf) * (T_ + 1) * SD_ + (size_t)(t + 1) * SD_ + sf] = xnew;
        }
        __syncthreads();   // D: new state visible; part2 reads done
    }
}

extern "C" void kernel_launch(void* const* d_in, const int* in_sizes, int n_in,
                              void* d_out, int out_size, void* d_ws, size_t ws_size,
                              hipStream_t stream) {
    const float* x0   = (const float*)d_in[0];
    const float* ctrl = (const float*)d_in[1];
    const float* W1   = (const float*)d_in[2];
    const float* b1   = (const float*)d_in[3];
    const float* W2   = (const float*)d_in[4];
    const float* b2   = (const float*)d_in[5];
    float* out = (float*)d_out;

    dim3 grid(B_ / ROWS_);      // 256 blocks -> 1 per CU (persistent)
    dim3 block(THREADS_);
    rollout_w2lds_stream_kernel<<<grid, block, 0, stream>>>(x0, ctrl, W1, b1, W2, b2, out);
}

// Round 5
// 962.080 us; speedup vs baseline: 9.0907x; 8.6939x over previous
//
#include <hip/hip_runtime.h>
#include <cstddef>

// DifferentiableRollout: x_{t+1} = x + DT * ( tanh([x,u]@W1 + b1) @ W2 + b2 )
// B=1024, T=200, SD=64, CD=32, H=512.  fp32 only (bf16 amplifies past the
// 1.245 absmax threshold; fp32 reorder noise alone is 0.25).
//
// History:
//  R5-R7: demanded 80 weight floats/thread in regs -> allocator never
//    granted >64 VGPRs at 1024 threads; weights streamed from L2 (790 us).
//  R8: W2->LDS (good) + asm-pinned W1 -> grant 64, pinned values spilled
//    to scratch in-loop: 28 GB HBM, 8746 us.
//  R9: pins removed, W1 as 48 explicit straight-line in-loop loads ->
//    LLVM's pre-RA scheduler hoisted ALL 48 loads above the FMA chain,
//    ~60 live values vs 64-reg grant -> allocator spilled the WEIGHTS to
//    scratch again: FETCH 11.8 GB / WRITE 15.5 GB (~57 fl read + 73
//    written /thread/step = the W1 working set), 8364 us.
//
// R10 (this round): structurally cap the live-load window.
//  - GEMM1 W1 stream in 8-load chunks, outer loop `#pragma unroll 1`:
//    scheduler cannot hoist loads across a non-unrolled loop boundary ->
//    peak pressure ~30 regs << 64.  Latency hidden by 16 waves/CU TLP.
//  - W2 (128 KB) stays LDS-resident (loaded once; lane-consecutive
//    conflict-free ds_read_b32 in GEMM2, each value reused x4 rows).
//  - plain __launch_bounds__(1024): the exact allocator context of the
//    no-spill R5/R6 builds.
//  - balanced tanh (g=0 rows 0-1, g=1 rows 2-3), pbuf aliases
//    partials/activations, ctrl prefetch by g=1 threads.
//  Model: W1 L2 stream 196 KB/CU/step ~3500 cyc + GEMM2 ~1600 + tail ~700
//  = ~5600 cyc/step -> ~465 us.
//  Verify: WRITE_SIZE ~51 MB, FETCH_SIZE ~14 MB (spill gone), VGPR 48-64.

constexpr int B_  = 1024;
constexpr int T_  = 200;
constexpr int SD_ = 64;
constexpr int CD_ = 32;
constexpr int H_  = 512;
constexpr int KD_ = SD_ + CD_;   // 96
constexpr float DT_ = 0.1f;
constexpr int ROWS_ = 4;
constexpr int THREADS_ = 1024;
constexpr int KHALF_ = 48;       // K split per g
constexpr int WCHUNK_ = 8;       // live W1 loads per chunk (spill guard)
constexpr int CHUNK_ = 32;       // W2 rows per wave (H / 16 waves)

__global__ __launch_bounds__(THREADS_)
void rollout_r10_kernel(
    const float* __restrict__ x0,     // [B, SD]
    const float* __restrict__ ctrl,   // [B, T, CD]
    const float* __restrict__ W1,     // [KD, H]
    const float* __restrict__ b1,     // [H]
    const float* __restrict__ W2,     // [H, SD]
    const float* __restrict__ b2,     // [SD]
    float* __restrict__ out)          // [B, T+1, SD]
{
    __shared__ float w2s[H_][SD_];           // 128 KB: W2, loaded once
    __shared__ float xcT[KD_][ROWS_];        // state+control, transposed
    __shared__ float pbuf[ROWS_][H_];        // GEMM1 partials, then tanh acts
    __shared__ float part2[ROWS_][16][SD_];  // GEMM2 partials [r][wv][s]

    const int tid = threadIdx.x;
    const int r0  = blockIdx.x * ROWS_;

    // ---- GEMM1 mapping: thread (g, j) streams W1[kbase..kbase+48)[j] ----
    const int j     = tid & (H_ - 1);   // 0..511
    const int g     = tid >> 9;         // 0 or 1 (wave-uniform)
    const int kbase = g * KHALF_;
    const float* __restrict__ wcol = W1 + (size_t)kbase * H_ + j;

    // ---- W2 -> LDS (flat coalesced copy, 8 float4 per thread) ----
    {
        const float4* __restrict__ src = (const float4*)W2;
        float4* dst = (float4*)&w2s[0][0];
        #pragma unroll
        for (int i = 0; i < 8; ++i)
            dst[i * THREADS_ + tid] = src[i * THREADS_ + tid];
    }

    // ---- GEMM2 mapping: wave wv covers H-slice [32wv, 32wv+32) ----
    const int wv = tid >> 6;            // 0..15 (wave id)
    const int sl = tid & 63;
    const int jb = wv * CHUNK_;

    const float bj = b1[j];

    // reduce/update mapping (tid < 256)
    const int rf = (tid >> 6) & 3;
    const int sf = tid & 63;
    const float bs = b2[sf];

    // ctrl loader: tids [512, 640) -- g==1 threads
    const int  lt = tid - 512;
    const bool loader = (lt >= 0) && (lt < ROWS_ * CD_);
    const int  lr = (lt >> 5) & 3;
    const int  lc = lt & 31;
    const size_t ctrl_base = (size_t)(r0 + lr) * T_ * CD_ + lc;

    // ---- init: x0 into xcT + states[:,0,:], ctrl[0] into xcT ----
    if (tid < ROWS_ * SD_) {
        const float v = x0[(size_t)(r0 + rf) * SD_ + sf];
        xcT[sf][rf] = v;
        out[(size_t)(r0 + rf) * (T_ + 1) * SD_ + sf] = v;
    }
    if (loader) xcT[SD_ + lc][lr] = ctrl[ctrl_base];
    __syncthreads();   // covers xcT init AND w2s copy

    for (int t = 0; t < T_; ++t) {
        // ---- prefetch next step's controls into a register ----
        float cpre = 0.f;
        if (loader && (t + 1 < T_))
            cpre = ctrl[ctrl_base + (size_t)(t + 1) * CD_];

        // ---- GEMM1 rank-48 partials: W1 streamed in 8-load chunks ----
        float a0 = 0.f, a1 = 0.f, a2 = 0.f, a3 = 0.f;
        #pragma unroll 1           // spill guard: <=8 live W1 loads
        for (int i0 = 0; i0 < KHALF_; i0 += WCHUNK_) {
            float w[WCHUNK_];
            #pragma unroll
            for (int u = 0; u < WCHUNK_; ++u)
                w[u] = wcol[(size_t)(i0 + u) * H_];        // L2 hit
            #pragma unroll
            for (int u = 0; u < WCHUNK_; ++u) {
                const float4 xv = *(const float4*)&xcT[kbase + i0 + u][0];
                a0 += xv.x * w[u];
                a1 += xv.y * w[u];
                a2 += xv.z * w[u];
                a3 += xv.w * w[u];
            }
        }
        // each half writes the partials the OTHER half will finish
        if (g == 0) { pbuf[2][j] = a2;  pbuf[3][j] = a3; }
        else        { pbuf[0][j] = a0;  pbuf[1][j] = a1; }
        __syncthreads();   // A: partials visible; step-t xcT reads done

        // ---- balanced tanh: g=0 rows 0-1, g=1 rows 2-3 ----
        if (g == 0) {
            pbuf[0][j] = tanhf(bj + a0 + pbuf[0][j]);
            pbuf[1][j] = tanhf(bj + a1 + pbuf[1][j]);
        } else {
            pbuf[2][j] = tanhf(bj + a2 + pbuf[2][j]);
            pbuf[3][j] = tanhf(bj + a3 + pbuf[3][j]);
            if (loader && (t + 1 < T_))
                xcT[SD_ + lc][lr] = cpre;   // step-t xcT reads done at A
        }
        __syncthreads();   // B: activations visible

        // ---- GEMM2: wave wv, j in [jb, jb+32), W2 from LDS ----
        {
            float p0 = 0.f, p1 = 0.f, p2 = 0.f, p3 = 0.f;
            #pragma unroll
            for (int i4 = 0; i4 < CHUNK_; i4 += 4) {
                // 4 W2 rows, lane-consecutive (conflict-free), reused x4 rows
                const float wa = w2s[jb + i4 + 0][sl];
                const float wb = w2s[jb + i4 + 1][sl];
                const float wc = w2s[jb + i4 + 2][sl];
                const float wd = w2s[jb + i4 + 3][sl];
                const float4 h0 = *(const float4*)&pbuf[0][jb + i4];
                const float4 h1 = *(const float4*)&pbuf[1][jb + i4];
                const float4 h2 = *(const float4*)&pbuf[2][jb + i4];
                const float4 h3 = *(const float4*)&pbuf[3][jb + i4];
                p0 += h0.x * wa + h0.y * wb + h0.z * wc + h0.w * wd;
                p1 += h1.x * wa + h1.y * wb + h1.z * wc + h1.w * wd;
                p2 += h2.x * wa + h2.y * wb + h2.z * wc + h2.w * wd;
                p3 += h3.x * wa + h3.y * wb + h3.z * wc + h3.w * wd;
            }
            part2[0][wv][sl] = p0;      // lane-consecutive: conflict-free
            part2[1][wv][sl] = p1;
            part2[2][wv][sl] = p2;
            part2[3][wv][sl] = p3;
        }
        __syncthreads();   // C: part2 visible

        // ---- 16-chunk reduce + state update: tid < 256 ----
        if (tid < ROWS_ * SD_) {
            float acc = part2[rf][0][sf];
            #pragma unroll
            for (int c = 1; c < 16; ++c) acc += part2[rf][c][sf];
            const float xnew = xcT[sf][rf] + DT_ * (acc + bs);
            xcT[sf][rf] = xnew;
            out[(size_t)(r0 + rf) * (T_ + 1) * SD_ + (size_t)(t + 1) * SD_ + sf] = xnew;
        }
        __syncthreads();   // D: new state visible; part2 reads done
    }
}

extern "C" void kernel_launch(void* const* d_in, const int* in_sizes, int n_in,
                              void* d_out, int out_size, void* d_ws, size_t ws_size,
                              hipStream_t stream) {
    const float* x0   = (const float*)d_in[0];
    const float* ctrl = (const float*)d_in[1];
    const float* W1   = (const float*)d_in[2];
    const float* b1   = (const float*)d_in[3];
    const float* W2   = (const float*)d_in[4];
    const float* b2   = (const float*)d_in[5];
    float* out = (float*)d_out;

    dim3 grid(B_ / ROWS_);      // 256 blocks -> 1 per CU (persistent)
    dim3 block(THREADS_);
    rollout_r10_kernel<<<grid, block, 0, stream>>>(x0, ctrl, W1, b1, W2, b2, out);
}